// Round 5
// baseline (553.601 us; speedup 1.0000x reference)
//
#include <hip/hip_runtime.h>
#include <math.h>

// Problem constants
#define BATCH 256
#define TT    2048
#define CC    39
#define CP    40        // padded channel stride (bf16) in carried buffers / xt LDS rows
#define Y1ST  44        // y1 LDS row stride (shorts): 22 dwords -> conflict-free reads
#define NBLK  8
#define KK    2
#define NCLS  8
#define BN_EPS 1e-5f

typedef __attribute__((ext_vector_type(8))) short short8;
typedef __attribute__((ext_vector_type(4))) float floatx4;

__device__ __forceinline__ unsigned short f2b(float f) {
    union { float f; unsigned u; } v; v.f = f;
    unsigned r = v.u + 0x7FFF + ((v.u >> 16) & 1);   // RNE
    return (unsigned short)(r >> 16);
}
__device__ __forceinline__ unsigned cvtpk(float lo, float hi) {
    unsigned r;
    asm("v_cvt_pk_bf16_f32 %0, %1, %2" : "=v"(r) : "v"(lo), "v"(hi));
    return r;
}
__device__ __forceinline__ float blo(unsigned u) {
    union { unsigned v; float f; } k; k.v = u << 16; return k.f;
}
__device__ __forceinline__ float bhi(unsigned u) {
    union { unsigned v; float f; } k; k.v = u & 0xffff0000u; return k.f;
}
__device__ __forceinline__ void gl_lds16(const void* g, void* l) {
    __builtin_amdgcn_global_load_lds(
        (const __attribute__((address_space(1))) unsigned int*)g,
        (__attribute__((address_space(3))) unsigned int*)l, 16, 0, 0);
}

// Weight fragment sizes (A-operand layout: row=co, K=96 in 3 slices)
#define WFB_PER   (2*3*3*512)          // layer,cotile,slice,lane,reg = 9216
#define WFB_TOTAL (2*NBLK*WFB_PER)     // 147456
#define BFB_TOTAL (2*NBLK*2*48)        // 1536
#define WFF_TOTAL (3*2*512)            // cotile,slice,lane,reg = 3072
#define BFF_TOTAL 48
#define ZPAD_SHORTS (256 * CP)         // 256 zero rows for t<0 / tail staging

// ---------------------------------------------------------------------------
// Fold BN into conv weights, baked as MFMA A-operand fragments.
// Block convs, K map (kin = (lane>>4)*8 + reg):
//   slice 0,1: p = kin>>4, ci = sl*16 + (kin&15)          (B cols sl*16 + (g&1)*8)
//   slice 2:   p = (lane>>4)&1, ci = 32 + reg, g<2 only   (B cols 32..39 always)
// Front 1x1:  ci = sl*32 + kin
// ---------------------------------------------------------------------------
__global__ void fold_kernel(const float* __restrict__ fw_w, const float* __restrict__ fw_b,
                            const float* __restrict__ fw_g, const float* __restrict__ fw_be,
                            const float* __restrict__ fw_m, const float* __restrict__ fw_v,
                            const float* __restrict__ bw_w, const float* __restrict__ bw_b,
                            const float* __restrict__ bw_g, const float* __restrict__ bw_be,
                            const float* __restrict__ bw_m, const float* __restrict__ bw_v,
                            const float* __restrict__ c1w, const float* __restrict__ c1b,
                            unsigned short* __restrict__ wfb, float* __restrict__ bfb,
                            unsigned short* __restrict__ wff, float* __restrict__ bff) {
    int idx = blockIdx.x * blockDim.x + threadIdx.x;
    if (idx < WFB_TOTAL) {
        int i = idx;
        int reg = i & 7;   i >>= 3;
        int lane = i & 63; i >>= 6;
        int sl = i % 3;    i /= 3;
        int ct = i % 3;    i /= 3;
        int layer = i & 1; i >>= 1;
        int blk = i & 7;   i >>= 3;
        int dir = i;
        int g = lane >> 4;
        int co = ct * 16 + (lane & 15);
        int p, ci; bool ok = true;
        if (sl < 2) {
            int kin = (g << 3) + reg;
            p = kin >> 4;
            ci = sl * 16 + (kin & 15);
        } else {
            p = g & 1;
            ci = 32 + reg;
            ok = (g < 2);
        }
        float val = 0.f;
        if (ok && co < CC && ci < CC) {
            const float* w = dir ? bw_w : fw_w;
            const float* gam = dir ? bw_g : fw_g;
            const float* var = dir ? bw_v : fw_v;
            int il = blk * 2 + layer;
            float sc = gam[il * CC + co] * rsqrtf(var[il * CC + co] + BN_EPS);
            val = w[((size_t)(il * CC + co) * CC + ci) * KK + p] * sc;
        }
        wfb[idx] = f2b(val);
        return;
    }
    idx -= WFB_TOTAL;
    if (idx < BFB_TOTAL) {
        int co = idx % 48;
        int i = idx / 48;
        int layer = i & 1; i >>= 1;
        int blk = i & 7;   i >>= 3;
        int dir = i;
        float val = 0.f;
        if (co < CC) {
            const float* b  = dir ? bw_b  : fw_b;
            const float* g  = dir ? bw_g  : fw_g;
            const float* be = dir ? bw_be : fw_be;
            const float* m  = dir ? bw_m  : fw_m;
            const float* v  = dir ? bw_v  : fw_v;
            int r = (blk * 2 + layer) * CC + co;
            float sc = g[r] * rsqrtf(v[r] + BN_EPS);
            val = (b[r] - m[r]) * sc + be[r];
        }
        bfb[idx] = val;
        return;
    }
    idx -= BFB_TOTAL;
    if (idx < WFF_TOTAL) {
        int i = idx;
        int reg = i & 7;   i >>= 3;
        int lane = i & 63; i >>= 6;
        int sl = i & 1;    i >>= 1;
        int ct = i;        // 0..2
        int co = ct * 16 + (lane & 15);
        int ci = sl * 32 + ((lane >> 4) << 3) + reg;
        float val = (co < CC && ci < CC) ? c1w[co * CC + ci] : 0.f;
        wff[idx] = f2b(val);
        return;
    }
    idx -= WFF_TOTAL;
    if (idx < BFF_TOTAL) {
        bff[idx] = (idx < CC) ? c1b[idx] : 0.f;
    }
}

// ---------------------------------------------------------------------------
// Front: [B,T,C] f32 -> carried [dir][B][T][CP] bf16 via 1x1 conv (MFMA, swapped).
// ---------------------------------------------------------------------------
__global__ __launch_bounds__(256) void front_mfma(const float* __restrict__ in,
                                                  const unsigned short* __restrict__ wf,
                                                  const float* __restrict__ bias,
                                                  unsigned short* __restrict__ out) {
    __shared__ unsigned short xt[256 * CP + 32];
    const int dir = blockIdx.z, b = blockIdx.y, t0 = blockIdx.x * 256;
    const int tid = threadIdx.x, lane = tid & 63, wave = tid >> 6;
    const int c = lane & 15, g = lane >> 4;
    const int stmin = dir ? (TT - t0 - 256) : t0;
    const float* src = in + ((size_t)b * TT + stmin) * CC;

    // stage: [256][39] f32 -> LDS [256][CP] bf16, packed pair-wise
    unsigned* xd = (unsigned*)xt;
    for (int e = tid; e < 256 * 20; e += 256) {
        int row = e / 20, cp = e - row * 20;
        int c0 = cp * 2;
        float f0 = src[(size_t)row * CC + c0];
        float f1 = (c0 + 1 < CC) ? src[(size_t)row * CC + c0 + 1] : 0.f;
        xd[row * 20 + cp] = cvtpk(f0, f1);
    }
    if (tid < 16) ((unsigned*)(xt + 256 * CP))[tid] = 0;    // slack
    __syncthreads();

    short8 Wf[3][2];
#pragma unroll
    for (int ct = 0; ct < 3; ++ct)
#pragma unroll
        for (int sl = 0; sl < 2; ++sl)
            Wf[ct][sl] = *(const short8*)(wf + (((ct * 2 + sl) * 64 + lane) << 3));
    float bs[3][4];
#pragma unroll
    for (int ct = 0; ct < 3; ++ct)
#pragma unroll
        for (int j = 0; j < 4; ++j) bs[ct][j] = bias[ct * 16 + g * 4 + j];

    for (int mt = wave; mt < 16; mt += 4) {
        int row = (mt << 4) + c;
        const unsigned short* bp = xt + row * CP;
        floatx4 acc[3];
#pragma unroll
        for (int ct = 0; ct < 3; ++ct)
            acc[ct] = floatx4{bs[ct][0], bs[ct][1], bs[ct][2], bs[ct][3]};
#pragma unroll
        for (int sl = 0; sl < 2; ++sl) {
            short8 B = *(const short8*)(bp + sl * 32 + g * 8);
#pragma unroll
            for (int ct = 0; ct < 3; ++ct)
                acc[ct] = __builtin_amdgcn_mfma_f32_16x16x32_bf16(Wf[ct][sl], B, acc[ct], 0, 0, 0);
        }
        int t = dir ? (t0 + 255 - row) : (t0 + row);
        unsigned short* op = out + ((size_t)(dir * BATCH + b) * TT + t) * CP;
#pragma unroll
        for (int ct = 0; ct < 3; ++ct) {
            if (ct == 2 && g >= 2) continue;    // co 40..47 don't exist
            uint2 v;
            v.x = cvtpk(acc[ct][0], acc[ct][1]);
            v.y = cvtpk(acc[ct][2], acc[ct][3]);
            *(uint2*)(op + ct * 16 + g * 4) = v;
        }
    }
}

// ---------------------------------------------------------------------------
// One Temporal_Aware_Block, fused, MFMA swapped-operand form. Templated on
// dilation D and tile TtC; async global->LDS staging.
// ---------------------------------------------------------------------------
template <int D, int TtC>
__global__ __launch_bounds__(256) void block_mfma(const unsigned short* __restrict__ xg,
                                                  unsigned short* __restrict__ yg,
                                                  const unsigned short* __restrict__ wf_all,
                                                  const float* __restrict__ bf_all,
                                                  float* __restrict__ skipPart,
                                                  const unsigned short* __restrict__ zpad,
                                                  int blk, int writeOut) {
    constexpr int ROWS_X   = TtC + 2 * D;
    constexpr int NCH      = ROWS_X * 5;          // 16B chunks per tile
    constexpr int NIT      = (NCH + 255) / 256;
    constexpr int XT_SHORTS = NIT * 256 * 8;
    constexpr int M1       = (TtC + D + 15) / 16;
    constexpr int ROWS_Y1  = M1 * 16;
    constexpr int ROWS_REAL = TtC + D;
    constexpr int Y1_SHORTS = ROWS_Y1 * Y1ST + 8;
    constexpr int M2W      = TtC / 64;

    extern __shared__ char ldsraw[];
    unsigned short* xt = (unsigned short*)ldsraw;         // [XT_SHORTS] linear chunks
    unsigned short* y1 = xt + XT_SHORTS;                  // [ROWS_Y1][Y1ST]
    float* stash = (float*)(y1 + Y1_SHORTS);              // [4][48]

    const int dir = blockIdx.z, b = blockIdx.y, tile = blockIdx.x;
    const int t0 = tile * TtC;
    const int tid = threadIdx.x, lane = tid & 63, wave = tid >> 6;
    const int c = lane & 15, g = lane >> 4;

    const size_t cbase = (size_t)(dir * BATCH + b) * TT * CP;
    const unsigned short* wf = wf_all + (size_t)(dir * NBLK + blk) * WFB_PER;
    const float* bf = bf_all + (size_t)(dir * NBLK + blk) * 96;

    // ---- async stage x rows [t0-2D, t0+TtC) into xt (linear) ----
    {
        const unsigned short* gx = xg + cbase;
#pragma unroll
        for (int it = 0; it < NIT; ++it) {
            int chunk = it * 256 + wave * 64 + lane;
            unsigned row = (unsigned)chunk / 5u;
            int sub = chunk - (int)row * 5;
            int t = t0 - 2 * D + (int)row;
            const unsigned short* src = (chunk < NCH && t >= 0)
                ? (gx + (size_t)t * CP + sub * 8)
                : (zpad + ((row & 255u) * CP + sub * 8));
            unsigned short* dst = xt + (size_t)(it * 256 + wave * 64) * 8;
            gl_lds16(src, dst);
        }
    }

    // weight fragments for stage 1 (overlap with staging latency)
    short8 Wf[3][3];
#pragma unroll
    for (int ct = 0; ct < 3; ++ct)
#pragma unroll
        for (int sl = 0; sl < 3; ++sl)
            Wf[ct][sl] = *(const short8*)(wf + ((((0 * 3 + ct) * 3 + sl) * 64 + lane) << 3));
    float bs[3][4];
#pragma unroll
    for (int ct = 0; ct < 3; ++ct)
#pragma unroll
        for (int j = 0; j < 4; ++j) bs[ct][j] = bf[ct * 16 + g * 4 + j];

    __syncthreads();   // drains vmcnt (global_load_lds) + lgkm

    // ---- stage 1: y1 = relu(conv1(x)) ----
    const int r01off = (g >> 1) * D;        // tap for slices 0,1
    const int r2off  = (g & 1) * D;         // tap for slice 2
    const int koff8  = (g & 1) << 3;

    for (int mt = wave; mt < M1; mt += 4) {
        int j0 = mt << 4;
        const unsigned short* bp01 = xt + (j0 + c + r01off) * CP + koff8;
        const unsigned short* bp2  = xt + (j0 + c + r2off) * CP + 32;
        short8 B0 = *(const short8*)(bp01);
        short8 B1 = *(const short8*)(bp01 + 16);
        short8 B2 = *(const short8*)(bp2);
        floatx4 acc[3];
#pragma unroll
        for (int ct = 0; ct < 3; ++ct) {
            acc[ct] = floatx4{bs[ct][0], bs[ct][1], bs[ct][2], bs[ct][3]};
            acc[ct] = __builtin_amdgcn_mfma_f32_16x16x32_bf16(Wf[ct][0], B0, acc[ct], 0, 0, 0);
            acc[ct] = __builtin_amdgcn_mfma_f32_16x16x32_bf16(Wf[ct][1], B1, acc[ct], 0, 0, 0);
            acc[ct] = __builtin_amdgcn_mfma_f32_16x16x32_bf16(Wf[ct][2], B2, acc[ct], 0, 0, 0);
        }
        int r = j0 + c;
        bool dead = (t0 - D + r < 0) || (r >= ROWS_REAL);
        unsigned short* yp = y1 + r * Y1ST;
#pragma unroll
        for (int ct = 0; ct < 3; ++ct) {
            if (ct == 2 && g >= 2) continue;
            uint2 v;
            v.x = cvtpk(fmaxf(acc[ct][0], 0.f), fmaxf(acc[ct][1], 0.f));
            v.y = cvtpk(fmaxf(acc[ct][2], 0.f), fmaxf(acc[ct][3], 0.f));
            if (dead) { v.x = 0u; v.y = 0u; }
            *(uint2*)(yp + ct * 16 + g * 4) = v;
        }
    }
    __syncthreads();

    // ---- stage 2: y2 = conv2(y1); out = x * sigmoid(y2) ----
#pragma unroll
    for (int ct = 0; ct < 3; ++ct)
#pragma unroll
        for (int sl = 0; sl < 3; ++sl)
            Wf[ct][sl] = *(const short8*)(wf + ((((1 * 3 + ct) * 3 + sl) * 64 + lane) << 3));
#pragma unroll
    for (int ct = 0; ct < 3; ++ct)
#pragma unroll
        for (int j = 0; j < 4; ++j) bs[ct][j] = bf[48 + ct * 16 + g * 4 + j];

    float sums[3][4];
#pragma unroll
    for (int ct = 0; ct < 3; ++ct)
#pragma unroll
        for (int j = 0; j < 4; ++j) sums[ct][j] = 0.f;

#pragma unroll
    for (int mi = 0; mi < M2W; ++mi) {
        int j0 = (wave * M2W + mi) << 4;
        const unsigned short* bp01 = y1 + (j0 + c + r01off) * Y1ST + koff8;
        const unsigned short* bp2  = y1 + (j0 + c + r2off) * Y1ST + 32;
        short8 B0 = *(const short8*)(bp01);
        short8 B1 = *(const short8*)(bp01 + 16);
        short8 B2 = *(const short8*)(bp2);
        floatx4 acc[3];
#pragma unroll
        for (int ct = 0; ct < 3; ++ct) {
            acc[ct] = floatx4{bs[ct][0], bs[ct][1], bs[ct][2], bs[ct][3]};
            acc[ct] = __builtin_amdgcn_mfma_f32_16x16x32_bf16(Wf[ct][0], B0, acc[ct], 0, 0, 0);
            acc[ct] = __builtin_amdgcn_mfma_f32_16x16x32_bf16(Wf[ct][1], B1, acc[ct], 0, 0, 0);
            acc[ct] = __builtin_amdgcn_mfma_f32_16x16x32_bf16(Wf[ct][2], B2, acc[ct], 0, 0, 0);
        }
        int r = j0 + c;
        const unsigned short* xrow = xt + (r + 2 * D) * CP;
        unsigned short* orow = yg + cbase + (size_t)(t0 + r) * CP;
#pragma unroll
        for (int ct = 0; ct < 3; ++ct) {
            uint2 xv = *(const uint2*)(xrow + ct * 16 + g * 4);
            float g0 = blo(xv.x) * __builtin_amdgcn_rcpf(1.f + __expf(-acc[ct][0]));
            float g1 = bhi(xv.x) * __builtin_amdgcn_rcpf(1.f + __expf(-acc[ct][1]));
            float g2 = blo(xv.y) * __builtin_amdgcn_rcpf(1.f + __expf(-acc[ct][2]));
            float g3 = bhi(xv.y) * __builtin_amdgcn_rcpf(1.f + __expf(-acc[ct][3]));
            sums[ct][0] += g0; sums[ct][1] += g1;
            sums[ct][2] += g2; sums[ct][3] += g3;
            if (writeOut && !(ct == 2 && g >= 2)) {
                uint2 v;
                v.x = cvtpk(g0, g1);
                v.y = cvtpk(g2, g3);
                *(uint2*)(orow + ct * 16 + g * 4) = v;
            }
        }
    }
    // reduce over the 16 time-cols (lanes differing in bits 0..3)
#pragma unroll
    for (int ct = 0; ct < 3; ++ct)
#pragma unroll
        for (int j = 0; j < 4; ++j) {
            float v = sums[ct][j];
            v += __shfl_xor(v, 1, 64);
            v += __shfl_xor(v, 2, 64);
            v += __shfl_xor(v, 4, 64);
            v += __shfl_xor(v, 8, 64);
            sums[ct][j] = v;
        }
    if (c == 0) {
#pragma unroll
        for (int ct = 0; ct < 3; ++ct)
#pragma unroll
            for (int j = 0; j < 4; ++j)
                stash[wave * 48 + ct * 16 + g * 4 + j] = sums[ct][j];
    }
    __syncthreads();
    if (tid < CC) {
        float s = stash[tid] + stash[48 + tid] + stash[96 + tid] + stash[144 + tid];
        skipPart[(((size_t)(blk * 2 + dir) * BATCH + b) * CC + tid) * 16 + tile] = s;
    }
}

static inline size_t lds_bytes_for(int D, int Tt) {
    int rows_x = Tt + 2 * D;
    int nch = rows_x * 5;
    int nit = (nch + 255) / 256;
    int xt_shorts = nit * 256 * 8;
    int m1 = (Tt + D + 15) / 16;
    int y1_shorts = m1 * 16 * Y1ST + 8;
    return (size_t)(xt_shorts + y1_shorts) * 2 + 192 * 4;
}

// ---------------------------------------------------------------------------
// Tail: means -> WeightLayer -> classifier -> log_softmax. Block per batch.
// ---------------------------------------------------------------------------
__global__ __launch_bounds__(64) void tail_kernel(const float* __restrict__ skipPart,
                                                  const float* __restrict__ wl,
                                                  const float* __restrict__ cw,
                                                  const float* __restrict__ cb,
                                                  float* __restrict__ out) {
    __shared__ float xs[CC];
    int b = blockIdx.x;
    int cth = threadIdx.x;
    if (cth < CC) {
        float x2 = 0.f;
        for (int i = 0; i < NBLK; ++i) {
            float wli = wl[i] * (1.0f / TT);
            int nt = (i == NBLK - 1) ? 16 : 8;
            for (int dirn = 0; dirn < 2; ++dirn) {
                const float* sp = skipPart + (((size_t)(i * 2 + dirn) * BATCH + b) * CC + cth) * 16;
                float s = 0.f;
                for (int tl = 0; tl < nt; ++tl) s += sp[tl];
                x2 = fmaf(s, wli, x2);
            }
        }
        xs[cth] = x2;
    }
    __syncthreads();
    if (threadIdx.x == 0) {
        float lg[NCLS];
        float mx = -1e30f;
        for (int o = 0; o < NCLS; ++o) {
            float a = cb[o];
#pragma unroll
            for (int cc2 = 0; cc2 < CC; ++cc2) a = fmaf(cw[o * CC + cc2], xs[cc2], a);
            lg[o] = a;
            mx = fmaxf(mx, a);
        }
        float se = 0.f;
        for (int o = 0; o < NCLS; ++o) se += expf(lg[o] - mx);
        float lse = logf(se) + mx;
        for (int o = 0; o < NCLS; ++o) out[b * NCLS + o] = lg[o] - lse;
    }
}

// ---------------------------------------------------------------------------
extern "C" void kernel_launch(void* const* d_in, const int* in_sizes, int n_in,
                              void* d_out, int out_size, void* d_ws, size_t ws_size,
                              hipStream_t stream) {
    const float* inputs = (const float*)d_in[0];
    const float* c1w    = (const float*)d_in[1];
    const float* c1b    = (const float*)d_in[2];
    const float* fw_w   = (const float*)d_in[3];
    const float* fw_b   = (const float*)d_in[4];
    const float* fw_g   = (const float*)d_in[5];
    const float* fw_be  = (const float*)d_in[6];
    const float* fw_m   = (const float*)d_in[7];
    const float* fw_v   = (const float*)d_in[8];
    const float* bw_w   = (const float*)d_in[9];
    const float* bw_b   = (const float*)d_in[10];
    const float* bw_g   = (const float*)d_in[11];
    const float* bw_be  = (const float*)d_in[12];
    const float* bw_m   = (const float*)d_in[13];
    const float* bw_v   = (const float*)d_in[14];
    const float* wl     = (const float*)d_in[15];
    const float* clsw   = (const float*)d_in[16];
    const float* clsb   = (const float*)d_in[17];

    const size_t bufsz = (size_t)2 * BATCH * TT * CP;          // ushorts
    unsigned short* buf0 = (unsigned short*)d_ws;
    unsigned short* buf1 = buf0 + bufsz;
    float* skip = (float*)(buf1 + bufsz);
    const size_t skipsz = (size_t)NBLK * 2 * BATCH * CC * 16;  // floats
    unsigned short* wfb = (unsigned short*)(skip + skipsz);
    float* bfb = (float*)(wfb + WFB_TOTAL);
    unsigned short* wff = (unsigned short*)(bfb + BFB_TOTAL);
    float* bff = (float*)(wff + WFF_TOTAL);
    unsigned short* zpad = (unsigned short*)(bff + BFF_TOTAL);

    hipMemsetAsync(zpad, 0, ZPAD_SHORTS * sizeof(unsigned short), stream);

    {
        int tot = WFB_TOTAL + BFB_TOTAL + WFF_TOTAL + BFF_TOTAL;
        fold_kernel<<<(tot + 255) / 256, 256, 0, stream>>>(
            fw_w, fw_b, fw_g, fw_be, fw_m, fw_v,
            bw_w, bw_b, bw_g, bw_be, bw_m, bw_v, c1w, c1b,
            wfb, bfb, wff, bff);
    }

    front_mfma<<<dim3(TT / 256, BATCH, 2), 256, 0, stream>>>(inputs, wff, bff, buf0);

    unsigned short* cur = buf0;
    unsigned short* nxt = buf1;
#define LAUNCH_BLOCK(DD, TTC)                                                        \
    block_mfma<DD, TTC><<<dim3(TT / TTC, BATCH, 2), 256, lds_bytes_for(DD, TTC),     \
                          stream>>>(cur, nxt, wfb, bfb, skip, zpad, i,               \
                                    (i < NBLK - 1) ? 1 : 0)
    for (int i = 0; i < NBLK; ++i) {
        switch (i) {
            case 0: LAUNCH_BLOCK(1, 256); break;
            case 1: LAUNCH_BLOCK(2, 256); break;
            case 2: LAUNCH_BLOCK(4, 256); break;
            case 3: LAUNCH_BLOCK(8, 256); break;
            case 4: LAUNCH_BLOCK(16, 256); break;
            case 5: LAUNCH_BLOCK(32, 256); break;
            case 6: LAUNCH_BLOCK(64, 256); break;
            case 7: LAUNCH_BLOCK(128, 128); break;
        }
        unsigned short* tmp = cur; cur = nxt; nxt = tmp;
    }
#undef LAUNCH_BLOCK

    tail_kernel<<<BATCH, 64, 0, stream>>>(skip, wl, clsw, clsb, (float*)d_out);
}